// Round 14
// baseline (123.978 us; speedup 1.0000x reference)
//
#include <hip/hip_runtime.h>
#include <math.h>

// Poincare fully-connected (hypll / Shimizu et al.), c = 1.
// B=1048576, IN=64, OUT=64, all fp32.
//
// R14 = R13 (split-bf16 MFMA dot staged via LDS; cvt_pk_bf16 frag split;
// fp16-packed w; 64B-coalesced stores) + software-pipelined multi-tile:
//   grid 2048 blocks x TPB=8 tiles. B/kc staged ONCE per block (8x
//   amortization of the 17.4 KB stage + barrier); per tile, the NEXT tile's
//   four x float4 loads are issued before computing the current tile, so
//   ~1500 cy of chain/MFMA hide the ~900 cy HBM latency that was previously
//   exposed once per 64 rows (16384 short-lived blocks in R13).
// Block = 256 = 4 waves; wave = 16 rows/tile.

typedef short bf16x8 __attribute__((ext_vector_type(8)));
typedef float f32x4  __attribute__((ext_vector_type(4)));
typedef __fp16 h2    __attribute__((ext_vector_type(2)));

#define TPB 8   // tiles (of 64 rows) per block

__device__ __forceinline__ unsigned short bf16_rne(float f) {
    unsigned int u = __float_as_uint(f);
    return (unsigned short)((u + 0x7fffu + ((u >> 16) & 1u)) >> 16);
}
__device__ __forceinline__ float bf16_f(unsigned short h) {
    return __uint_as_float((unsigned int)h << 16);
}

// ws u32 layout:
//   [0,2048)    : B_hi dwords, idx ((nb*2+ks)*64 + lane)*4 + j
//   [2048,4096) : B_lo dwords, same idx
//   [4096,4352) : kc float4[o] = {K1, K2, K4, 0}
__global__ void hl_prep(const float* __restrict__ z, const float* __restrict__ bias,
                        float* __restrict__ ws) {
    unsigned int* wsu = reinterpret_cast<unsigned int*>(ws);
    const int t = threadIdx.x;
    #pragma unroll
    for (int h = 0; h < 2; ++h) {
        const int tt = t + h * 256;          // 512 (nb,ks,l) triples
        const int nb = tt >> 7, ks = (tt >> 6) & 1, l = tt & 63;
        const int o  = nb * 16 + (l & 15);
        const int k0 = ks * 32 + (l >> 4) * 8;
        #pragma unroll
        for (int j = 0; j < 4; ++j) {
            const float a = z[(k0 + 2*j    ) * 64 + o];
            const float b = z[(k0 + 2*j + 1) * 64 + o];
            const unsigned short ha = bf16_rne(a), hb = bf16_rne(b);
            const float ra = a - bf16_f(ha);
            const float rb = b - bf16_f(hb);
            const int idx = ((nb * 2 + ks) * 64 + l) * 4 + j;
            wsu[idx]        = (unsigned)ha | ((unsigned)hb << 16);
            wsu[2048 + idx] = (unsigned)bf16_rne(ra) | ((unsigned)bf16_rne(rb) << 16);
        }
    }
    if (t < 64) {
        const int o = t;
        float n2 = 0.f;
        for (int k = 0; k < 64; ++k) { const float v = z[k*64 + o]; n2 = fmaf(v, v, n2); }
        const float zn = fmaxf(sqrtf(n2), 1e-15f);
        const float e  = expf(2.f * bias[o]);
        const float ei = 1.f / e;
        float4 c;
        c.x = 0.5f * (e + ei) / zn;    // K1
        c.y = 0.5f * (e - ei);         // K2
        c.z = 2.f * zn;                // K4
        c.w = 0.f;
        reinterpret_cast<float4*>(ws + 4096)[o] = c;
    }
}

__device__ __forceinline__ float hl_chain(float xz, float lam,
                                          float K1, float K2, float K4) {
    const float u  = fmaf(lam, fmaf(xz, K1, -K2), K2);
    const float au = fabsf(u);
    const float sq = __builtin_amdgcn_sqrtf(fmaf(au, au, 1.f));
    const float lg = __builtin_amdgcn_logf(au + sq);      // log2
    const float e  = __builtin_amdgcn_exp2f(K4 * lg);     // 2^x
    const float ei = __builtin_amdgcn_rcpf(e);
    return copysignf(fmaf(0.5f, e, -0.5f * ei), u);       // sinh
}

// split one f32 pair into packed-bf16 hi + residual-lo dwords (6 instr)
__device__ __forceinline__ void split2(float a, float b,
                                       unsigned int& ph, unsigned int& pl) {
    asm("v_cvt_pk_bf16_f32 %0, %1, %2" : "=v"(ph) : "v"(a), "v"(b));
    const float fa = __uint_as_float(ph << 16);            // bf16(a) as f32
    const float fb = __uint_as_float(ph & 0xffff0000u);    // bf16(b) as f32
    asm("v_cvt_pk_bf16_f32 %0, %1, %2" : "=v"(pl) : "v"(a - fa), "v"(b - fb));
}

__device__ __forceinline__ void build_frag(const float4& f0, const float4& f1,
                                           uint4& hi, uint4& lo) {
    split2(f0.x, f0.y, hi.x, lo.x);
    split2(f0.z, f0.w, hi.y, lo.y);
    split2(f1.x, f1.y, hi.z, lo.z);
    split2(f1.z, f1.w, hi.w, lo.w);
}

#define MFMA(A, B, C) __builtin_amdgcn_mfma_f32_16x16x32_bf16( \
    __builtin_bit_cast(bf16x8, A), __builtin_bit_cast(bf16x8, B), C, 0, 0, 0)

__global__ __launch_bounds__(256, 5)
void hl_mfma(const float* __restrict__ x, const float* __restrict__ ws_f,
             float* __restrict__ out) {
    __shared__ unsigned int ldsb[4096];      // B hi [0,2048) + lo [2048,4096)
    __shared__ float4       ldsk[64];        // per-o constants

    const unsigned int* __restrict__ wsu = reinterpret_cast<const unsigned int*>(ws_f);
    const int tid  = threadIdx.x;
    const int wave = tid >> 6;
    const int l    = tid & 63;
    const int half = l >> 4;                 // k-chunk 0..3
    const int o0   = l & 15;
    const long tile0 = (long)blockIdx.x * TPB;
    // per-lane byte offset within a 64-row tile
    const long xoff = ((long)wave * 16 + o0) * 64 + half * 8;

    // ---- issue tile-0 x loads FIRST (latency overlaps staging+barrier) ----
    const float* __restrict__ xp = x + tile0 * 4096 + xoff;
    float4 xa0 = *reinterpret_cast<const float4*>(xp);
    float4 xa1 = *reinterpret_cast<const float4*>(xp + 4);
    float4 xb0 = *reinterpret_cast<const float4*>(xp + 32);
    float4 xb1 = *reinterpret_cast<const float4*>(xp + 36);

    // ---- cooperative stage: B hi/lo + kc -> LDS (once per block) ----
    {
        const uint4* __restrict__ src = reinterpret_cast<const uint4*>(wsu);
        uint4* __restrict__ dst = reinterpret_cast<uint4*>(ldsb);
        #pragma unroll
        for (int t = 0; t < 4; ++t) dst[t * 256 + tid] = src[t * 256 + tid];
        if (tid < 64) ldsk[tid] = reinterpret_cast<const float4*>(ws_f + 4096)[tid];
    }
    __syncthreads();                         // staging complete

    const uint4* __restrict__ lb = reinterpret_cast<const uint4*>(ldsb);

    #pragma unroll 1
    for (int t = 0; t < TPB; ++t) {
        // ---- prefetch next tile's x (clamped at tail; L1-hit re-read) ----
        const int tn = (t + 1 < TPB) ? (t + 1) : t;
        const float* __restrict__ np = x + (tile0 + tn) * 4096 + xoff;
        const float4 na0 = *reinterpret_cast<const float4*>(np);
        const float4 na1 = *reinterpret_cast<const float4*>(np + 4);
        const float4 nb0 = *reinterpret_cast<const float4*>(np + 32);
        const float4 nb1 = *reinterpret_cast<const float4*>(np + 36);

        const long rowbase = (tile0 + t) * 64 + wave * 16;

        // ---- row norm (exact f32) ----
        float n2 = 0.f;
        n2 = fmaf(xa0.x,xa0.x,n2); n2 = fmaf(xa0.y,xa0.y,n2);
        n2 = fmaf(xa0.z,xa0.z,n2); n2 = fmaf(xa0.w,xa0.w,n2);
        n2 = fmaf(xa1.x,xa1.x,n2); n2 = fmaf(xa1.y,xa1.y,n2);
        n2 = fmaf(xa1.z,xa1.z,n2); n2 = fmaf(xa1.w,xa1.w,n2);
        n2 = fmaf(xb0.x,xb0.x,n2); n2 = fmaf(xb0.y,xb0.y,n2);
        n2 = fmaf(xb0.z,xb0.z,n2); n2 = fmaf(xb0.w,xb0.w,n2);
        n2 = fmaf(xb1.x,xb1.x,n2); n2 = fmaf(xb1.y,xb1.y,n2);
        n2 = fmaf(xb1.z,xb1.z,n2); n2 = fmaf(xb1.w,xb1.w,n2);
        n2 += __shfl_xor(n2, 16);
        n2 += __shfl_xor(n2, 32);
        const float lamv = 2.f * __builtin_amdgcn_rcpf(1.f - n2);

        // ---- A fragments (hi/lo split via cvt_pk_bf16) ----
        uint4 Ah0, Al0, Ah1, Al1;
        build_frag(xa0, xa1, Ah0, Al0);
        build_frag(xb0, xb1, Ah1, Al1);

        float lam_r[4];
        #pragma unroll
        for (int reg = 0; reg < 4; ++reg)
            lam_r[reg] = __shfl(lamv, half * 4 + reg);

        // ---- per-nb: B frags (LDS) -> 6 MFMA -> chain -> pack w ----
        unsigned int wpk[8];
        float p[4] = {0.f, 0.f, 0.f, 0.f};
        #pragma unroll 1
        for (int nb = 0; nb < 4; ++nb) {
            const uint4 bh0 = lb[      (nb*2+0)*64 + l];
            const uint4 bl0 = lb[512 + (nb*2+0)*64 + l];
            const uint4 bh1 = lb[      (nb*2+1)*64 + l];
            const uint4 bl1 = lb[512 + (nb*2+1)*64 + l];
            const float4 kc = ldsk[nb*16 + o0];

            f32x4 a = {0.f, 0.f, 0.f, 0.f};
            a = MFMA(Al0, bh0, a);   // low-order terms first
            a = MFMA(Ah0, bl0, a);
            a = MFMA(Ah0, bh0, a);
            a = MFMA(Al1, bh1, a);
            a = MFMA(Ah1, bl1, a);
            a = MFMA(Ah1, bh1, a);

            float w0 = hl_chain(a[0], lam_r[0], kc.x, kc.y, kc.z);
            float w1 = hl_chain(a[1], lam_r[1], kc.x, kc.y, kc.z);
            float w2 = hl_chain(a[2], lam_r[2], kc.x, kc.y, kc.z);
            float w3 = hl_chain(a[3], lam_r[3], kc.x, kc.y, kc.z);
            p[0] = fmaf(w0, w0, p[0]);
            p[1] = fmaf(w1, w1, p[1]);
            p[2] = fmaf(w2, w2, p[2]);
            p[3] = fmaf(w3, w3, p[3]);
            h2 q0 = __builtin_amdgcn_cvt_pkrtz(w0, w1);
            h2 q1 = __builtin_amdgcn_cvt_pkrtz(w2, w3);
            wpk[nb*2]   = __builtin_bit_cast(unsigned int, q0);
            wpk[nb*2+1] = __builtin_bit_cast(unsigned int, q1);
        }

        // ---- reduce sum(w^2) over 16-lane groups ----
        #pragma unroll
        for (int reg = 0; reg < 4; ++reg) {
            p[reg] += __shfl_xor(p[reg], 1);
            p[reg] += __shfl_xor(p[reg], 2);
            p[reg] += __shfl_xor(p[reg], 4);
            p[reg] += __shfl_xor(p[reg], 8);
        }

        // ---- scale + stores: 64B-coalesced per 16-lane group ----
        #pragma unroll
        for (int reg = 0; reg < 4; ++reg) {
            const float scale =
                __builtin_amdgcn_rcpf(1.f + __builtin_amdgcn_sqrtf(1.f + p[reg]));
            float* __restrict__ orow = out + (rowbase + half * 4 + reg) * 64 + o0;
            #pragma unroll
            for (int nb = 0; nb < 4; ++nb) {
                const h2 q = __builtin_bit_cast(h2, wpk[nb*2 + (reg >> 1)]);
                orow[nb * 16] = (float)q[reg & 1] * scale;
            }
        }

        // ---- rotate prefetched x into place ----
        xa0 = na0; xa1 = na1; xb0 = nb0; xb1 = nb1;
    }
}

// slow correctness fallback (only if ws too small; never expected to run)
__global__ void hl_naive(const float* __restrict__ x, const float* __restrict__ z,
                         const float* __restrict__ bias, float* __restrict__ out,
                         long rows) {
    const long r = (long)blockIdx.x * blockDim.x + threadIdx.x;
    if (r >= rows) return;
    float xs[64];
    float n2 = 0.f;
    for (int k = 0; k < 64; ++k) { xs[k] = x[r*64 + k]; n2 = fmaf(xs[k], xs[k], n2); }
    const float lam = 2.f / (1.f - n2);
    float wv[64], sw2 = 0.f;
    for (int o = 0; o < 64; ++o) {
        float a = 0.f, q = 0.f;
        for (int k = 0; k < 64; ++k) {
            const float zv = z[k*64 + o];
            a = fmaf(zv, xs[k], a);
            q = fmaf(zv, zv, q);
        }
        const float zn = fmaxf(sqrtf(q), 1e-15f);
        const float e  = expf(2.f * bias[o]);
        const float ei = 1.f / e;
        wv[o] = hl_chain(a, lam, 0.5f*(e+ei)/zn, 0.5f*(e-ei), 2.f*zn);
        sw2 = fmaf(wv[o], wv[o], sw2);
    }
    const float s = 1.f / (1.f + sqrtf(1.f + sw2));
    for (int o = 0; o < 64; ++o) out[r*64 + o] = wv[o] * s;
}

extern "C" void kernel_launch(void* const* d_in, const int* in_sizes, int n_in,
                              void* d_out, int out_size, void* d_ws, size_t ws_size,
                              hipStream_t stream) {
    const float* x    = (const float*)d_in[0];
    const float* z    = (const float*)d_in[1];
    const float* bias = (const float*)d_in[2];
    float* out = (float*)d_out;
    float* ws  = (float*)d_ws;

    const long rows = (long)in_sizes[0] / 64;       // 1048576

    if (ws_size >= (size_t)(4096 + 256) * sizeof(unsigned int)) {
        hl_prep<<<1, 256, 0, stream>>>(z, bias, ws);
        hl_mfma<<<(int)(rows / (64 * TPB)), 256, 0, stream>>>(x, ws, out);
    } else {
        hl_naive<<<(int)((rows + 255) / 256), 256, 0, stream>>>(x, z, bias, out, rows);
    }
}

// Round 15
// 115.485 us; speedup vs baseline: 1.0735x; 1.0735x over previous
//
#include <hip/hip_runtime.h>
#include <math.h>

// Poincare fully-connected (hypll / Shimizu et al.), c = 1.
// B=1048576, IN=64, OUT=64, all fp32.
//
// R15 = R13 body exactly (split-bf16 MFMA dot; B/kc staged in LDS once per
// block; cvt_pk_bf16 frag split; fp16-packed w; 64B-coalesced stores),
// with __launch_bounds__(256,7) instead of (256,6):
//   R14's A/B showed the kernel is latency-bound and wave-count-sensitive
//   (5 waves/SIMD regressed vs 6). 7 waves/SIMD (VGPR cap 73; live state
//   ~70 regs) adds +17% TLP. LDS: 7 blocks x 17.4 KB = 122 KB < 160 KB.
// Block = 256 = 4 waves; wave = 16 rows; grid = rows/64.

typedef short bf16x8 __attribute__((ext_vector_type(8)));
typedef float f32x4  __attribute__((ext_vector_type(4)));
typedef __fp16 h2    __attribute__((ext_vector_type(2)));

__device__ __forceinline__ unsigned short bf16_rne(float f) {
    unsigned int u = __float_as_uint(f);
    return (unsigned short)((u + 0x7fffu + ((u >> 16) & 1u)) >> 16);
}
__device__ __forceinline__ float bf16_f(unsigned short h) {
    return __uint_as_float((unsigned int)h << 16);
}

// ws u32 layout:
//   [0,2048)    : B_hi dwords, idx ((nb*2+ks)*64 + lane)*4 + j
//   [2048,4096) : B_lo dwords, same idx
//   [4096,4352) : kc float4[o] = {K1, K2, K4, 0}
__global__ void hl_prep(const float* __restrict__ z, const float* __restrict__ bias,
                        float* __restrict__ ws) {
    unsigned int* wsu = reinterpret_cast<unsigned int*>(ws);
    const int t = threadIdx.x;
    #pragma unroll
    for (int h = 0; h < 2; ++h) {
        const int tt = t + h * 256;          // 512 (nb,ks,l) triples
        const int nb = tt >> 7, ks = (tt >> 6) & 1, l = tt & 63;
        const int o  = nb * 16 + (l & 15);
        const int k0 = ks * 32 + (l >> 4) * 8;
        #pragma unroll
        for (int j = 0; j < 4; ++j) {
            const float a = z[(k0 + 2*j    ) * 64 + o];
            const float b = z[(k0 + 2*j + 1) * 64 + o];
            const unsigned short ha = bf16_rne(a), hb = bf16_rne(b);
            const float ra = a - bf16_f(ha);
            const float rb = b - bf16_f(hb);
            const int idx = ((nb * 2 + ks) * 64 + l) * 4 + j;
            wsu[idx]        = (unsigned)ha | ((unsigned)hb << 16);
            wsu[2048 + idx] = (unsigned)bf16_rne(ra) | ((unsigned)bf16_rne(rb) << 16);
        }
    }
    if (t < 64) {
        const int o = t;
        float n2 = 0.f;
        for (int k = 0; k < 64; ++k) { const float v = z[k*64 + o]; n2 = fmaf(v, v, n2); }
        const float zn = fmaxf(sqrtf(n2), 1e-15f);
        const float e  = expf(2.f * bias[o]);
        const float ei = 1.f / e;
        float4 c;
        c.x = 0.5f * (e + ei) / zn;    // K1
        c.y = 0.5f * (e - ei);         // K2
        c.z = 2.f * zn;                // K4
        c.w = 0.f;
        reinterpret_cast<float4*>(ws + 4096)[o] = c;
    }
}

__device__ __forceinline__ float hl_chain(float xz, float lam,
                                          float K1, float K2, float K4) {
    const float u  = fmaf(lam, fmaf(xz, K1, -K2), K2);
    const float au = fabsf(u);
    const float sq = __builtin_amdgcn_sqrtf(fmaf(au, au, 1.f));
    const float lg = __builtin_amdgcn_logf(au + sq);      // log2
    const float e  = __builtin_amdgcn_exp2f(K4 * lg);     // 2^x
    const float ei = __builtin_amdgcn_rcpf(e);
    return copysignf(fmaf(0.5f, e, -0.5f * ei), u);       // sinh
}

// split one f32 pair into packed-bf16 hi + residual-lo dwords (6 instr)
__device__ __forceinline__ void split2(float a, float b,
                                       unsigned int& ph, unsigned int& pl) {
    asm("v_cvt_pk_bf16_f32 %0, %1, %2" : "=v"(ph) : "v"(a), "v"(b));
    const float fa = __uint_as_float(ph << 16);            // bf16(a) as f32
    const float fb = __uint_as_float(ph & 0xffff0000u);    // bf16(b) as f32
    asm("v_cvt_pk_bf16_f32 %0, %1, %2" : "=v"(pl) : "v"(a - fa), "v"(b - fb));
}

__device__ __forceinline__ void build_frag(const float4& f0, const float4& f1,
                                           uint4& hi, uint4& lo) {
    split2(f0.x, f0.y, hi.x, lo.x);
    split2(f0.z, f0.w, hi.y, lo.y);
    split2(f1.x, f1.y, hi.z, lo.z);
    split2(f1.z, f1.w, hi.w, lo.w);
}

#define MFMA(A, B, C) __builtin_amdgcn_mfma_f32_16x16x32_bf16( \
    __builtin_bit_cast(bf16x8, A), __builtin_bit_cast(bf16x8, B), C, 0, 0, 0)

__global__ __launch_bounds__(256, 7)
void hl_mfma(const float* __restrict__ x, const float* __restrict__ ws_f,
             float* __restrict__ out) {
    __shared__ unsigned int ldsb[4096];      // B hi [0,2048) + lo [2048,4096)
    __shared__ float4       ldsk[64];        // per-o constants

    const unsigned int* __restrict__ wsu = reinterpret_cast<const unsigned int*>(ws_f);
    const int tid  = threadIdx.x;
    const int wave = tid >> 6;
    const int l    = tid & 63;
    const int half = l >> 4;                 // k-chunk 0..3
    const int o0   = l & 15;
    const long rowbase = (long)blockIdx.x * 64 + wave * 16;

    // ---- issue own x loads FIRST (HBM latency overlaps staging+barrier) ----
    const float* __restrict__ xp = x + (rowbase + o0) * 64 + half * 8;
    const float4 xa0 = *reinterpret_cast<const float4*>(xp);
    const float4 xa1 = *reinterpret_cast<const float4*>(xp + 4);
    const float4 xb0 = *reinterpret_cast<const float4*>(xp + 32);
    const float4 xb1 = *reinterpret_cast<const float4*>(xp + 36);

    // ---- cooperative stage: B hi/lo + kc -> LDS (once per block) ----
    {
        const uint4* __restrict__ src = reinterpret_cast<const uint4*>(wsu);
        uint4* __restrict__ dst = reinterpret_cast<uint4*>(ldsb);
        #pragma unroll
        for (int t = 0; t < 4; ++t) dst[t * 256 + tid] = src[t * 256 + tid];
        if (tid < 64) ldsk[tid] = reinterpret_cast<const float4*>(ws_f + 4096)[tid];
    }

    // ---- row norm (exact f32): partial over this lane's 16 k, reduce x4 ----
    float n2 = 0.f;
    n2 = fmaf(xa0.x,xa0.x,n2); n2 = fmaf(xa0.y,xa0.y,n2);
    n2 = fmaf(xa0.z,xa0.z,n2); n2 = fmaf(xa0.w,xa0.w,n2);
    n2 = fmaf(xa1.x,xa1.x,n2); n2 = fmaf(xa1.y,xa1.y,n2);
    n2 = fmaf(xa1.z,xa1.z,n2); n2 = fmaf(xa1.w,xa1.w,n2);
    n2 = fmaf(xb0.x,xb0.x,n2); n2 = fmaf(xb0.y,xb0.y,n2);
    n2 = fmaf(xb0.z,xb0.z,n2); n2 = fmaf(xb0.w,xb0.w,n2);
    n2 = fmaf(xb1.x,xb1.x,n2); n2 = fmaf(xb1.y,xb1.y,n2);
    n2 = fmaf(xb1.z,xb1.z,n2); n2 = fmaf(xb1.w,xb1.w,n2);
    n2 += __shfl_xor(n2, 16);
    n2 += __shfl_xor(n2, 32);
    const float lamv = 2.f * __builtin_amdgcn_rcpf(1.f - n2);   // row (l&15)

    // ---- A fragments (hi/lo split via cvt_pk_bf16) ----
    uint4 Ah0, Al0, Ah1, Al1;
    build_frag(xa0, xa1, Ah0, Al0);
    build_frag(xb0, xb1, Ah1, Al1);

    // ---- lam for this lane's 4 C-rows (row = half*4 + reg) ----
    float lam_r[4];
    #pragma unroll
    for (int reg = 0; reg < 4; ++reg)
        lam_r[reg] = __shfl(lamv, half * 4 + reg);

    __syncthreads();                         // staging complete

    // ---- per-nb: B frags (LDS) -> 6 MFMA -> chain 4 -> pack w to fp16 ----
    const uint4* __restrict__ lb = reinterpret_cast<const uint4*>(ldsb);
    unsigned int wpk[8];                     // 16 w values, fp16-packed
    float p[4] = {0.f, 0.f, 0.f, 0.f};       // per-C-row sum(w^2) partials
    #pragma unroll 1
    for (int nb = 0; nb < 4; ++nb) {
        const uint4 bh0 = lb[      (nb*2+0)*64 + l];
        const uint4 bl0 = lb[512 + (nb*2+0)*64 + l];
        const uint4 bh1 = lb[      (nb*2+1)*64 + l];
        const uint4 bl1 = lb[512 + (nb*2+1)*64 + l];
        const float4 kc = ldsk[nb*16 + o0];

        f32x4 a = {0.f, 0.f, 0.f, 0.f};
        a = MFMA(Al0, bh0, a);   // low-order terms first
        a = MFMA(Ah0, bl0, a);
        a = MFMA(Ah0, bh0, a);
        a = MFMA(Al1, bh1, a);
        a = MFMA(Ah1, bl1, a);
        a = MFMA(Ah1, bh1, a);

        float w0 = hl_chain(a[0], lam_r[0], kc.x, kc.y, kc.z);
        float w1 = hl_chain(a[1], lam_r[1], kc.x, kc.y, kc.z);
        float w2 = hl_chain(a[2], lam_r[2], kc.x, kc.y, kc.z);
        float w3 = hl_chain(a[3], lam_r[3], kc.x, kc.y, kc.z);
        p[0] = fmaf(w0, w0, p[0]);
        p[1] = fmaf(w1, w1, p[1]);
        p[2] = fmaf(w2, w2, p[2]);
        p[3] = fmaf(w3, w3, p[3]);
        h2 q0 = __builtin_amdgcn_cvt_pkrtz(w0, w1);
        h2 q1 = __builtin_amdgcn_cvt_pkrtz(w2, w3);
        wpk[nb*2]   = __builtin_bit_cast(unsigned int, q0);
        wpk[nb*2+1] = __builtin_bit_cast(unsigned int, q1);
    }

    // ---- reduce sum(w^2) over the 16-lane group (all 64 o of each row) ----
    #pragma unroll
    for (int reg = 0; reg < 4; ++reg) {
        p[reg] += __shfl_xor(p[reg], 1);
        p[reg] += __shfl_xor(p[reg], 2);
        p[reg] += __shfl_xor(p[reg], 4);
        p[reg] += __shfl_xor(p[reg], 8);
    }

    // ---- scale + stores: 64B-coalesced per 16-lane group ----
    #pragma unroll
    for (int reg = 0; reg < 4; ++reg) {
        const float scale =
            __builtin_amdgcn_rcpf(1.f + __builtin_amdgcn_sqrtf(1.f + p[reg]));
        float* __restrict__ orow = out + (rowbase + half * 4 + reg) * 64 + o0;
        #pragma unroll
        for (int nb = 0; nb < 4; ++nb) {
            const h2 q = __builtin_bit_cast(h2, wpk[nb*2 + (reg >> 1)]);
            orow[nb * 16] = (float)q[reg & 1] * scale;
        }
    }
}

// slow correctness fallback (only if ws too small; never expected to run)
__global__ void hl_naive(const float* __restrict__ x, const float* __restrict__ z,
                         const float* __restrict__ bias, float* __restrict__ out,
                         long rows) {
    const long r = (long)blockIdx.x * blockDim.x + threadIdx.x;
    if (r >= rows) return;
    float xs[64];
    float n2 = 0.f;
    for (int k = 0; k < 64; ++k) { xs[k] = x[r*64 + k]; n2 = fmaf(xs[k], xs[k], n2); }
    const float lam = 2.f / (1.f - n2);
    float wv[64], sw2 = 0.f;
    for (int o = 0; o < 64; ++o) {
        float a = 0.f, q = 0.f;
        for (int k = 0; k < 64; ++k) {
            const float zv = z[k*64 + o];
            a = fmaf(zv, xs[k], a);
            q = fmaf(zv, zv, q);
        }
        const float zn = fmaxf(sqrtf(q), 1e-15f);
        const float e  = expf(2.f * bias[o]);
        const float ei = 1.f / e;
        wv[o] = hl_chain(a, lam, 0.5f*(e+ei)/zn, 0.5f*(e-ei), 2.f*zn);
        sw2 = fmaf(wv[o], wv[o], sw2);
    }
    const float s = 1.f / (1.f + sqrtf(1.f + sw2));
    for (int o = 0; o < 64; ++o) out[r*64 + o] = wv[o] * s;
}

extern "C" void kernel_launch(void* const* d_in, const int* in_sizes, int n_in,
                              void* d_out, int out_size, void* d_ws, size_t ws_size,
                              hipStream_t stream) {
    const float* x    = (const float*)d_in[0];
    const float* z    = (const float*)d_in[1];
    const float* bias = (const float*)d_in[2];
    float* out = (float*)d_out;
    float* ws  = (float*)d_ws;

    const long rows = (long)in_sizes[0] / 64;       // 1048576

    if (ws_size >= (size_t)(4096 + 256) * sizeof(unsigned int)) {
        hl_prep<<<1, 256, 0, stream>>>(z, bias, ws);
        hl_mfma<<<(int)(rows / 64), 256, 0, stream>>>(x, ws, out);
    } else {
        hl_naive<<<(int)((rows + 255) / 256), 256, 0, stream>>>(x, z, bias, out, rows);
    }
}

// Round 16
// 99.924 us; speedup vs baseline: 1.2407x; 1.1557x over previous
//
#include <hip/hip_runtime.h>
#include <math.h>

// Poincare fully-connected (hypll / Shimizu et al.), c = 1.
// B=1048576, IN=64, OUT=64, all fp32.
//
// R16 = R15 (split-bf16 MFMA dot; B/kc staged in LDS once per block;
// cvt_pk_bf16 frag split; fp16-packed w; 64B-coalesced stores; (256,7))
// + NON-TEMPORAL output stores:
//   R14/R15 A/B showed TLP no longer pays (+17% waves -> +1.5%): we are
//   pressing the memory system. x (256 MB) == L3 size; the 256 MB/replay
//   output stream evicts it, forcing ~135 MB/replay of HBM re-fetch.
//   __builtin_nontemporal_store (nt/sc1) keeps writes from occupying L3,
//   letting x stay L3-resident across graph replays.
// Block = 256 = 4 waves; wave = 16 rows; grid = rows/64.

typedef short bf16x8 __attribute__((ext_vector_type(8)));
typedef float f32x4  __attribute__((ext_vector_type(4)));
typedef __fp16 h2    __attribute__((ext_vector_type(2)));

__device__ __forceinline__ unsigned short bf16_rne(float f) {
    unsigned int u = __float_as_uint(f);
    return (unsigned short)((u + 0x7fffu + ((u >> 16) & 1u)) >> 16);
}
__device__ __forceinline__ float bf16_f(unsigned short h) {
    return __uint_as_float((unsigned int)h << 16);
}

// ws u32 layout:
//   [0,2048)    : B_hi dwords, idx ((nb*2+ks)*64 + lane)*4 + j
//   [2048,4096) : B_lo dwords, same idx
//   [4096,4352) : kc float4[o] = {K1, K2, K4, 0}
__global__ void hl_prep(const float* __restrict__ z, const float* __restrict__ bias,
                        float* __restrict__ ws) {
    unsigned int* wsu = reinterpret_cast<unsigned int*>(ws);
    const int t = threadIdx.x;
    #pragma unroll
    for (int h = 0; h < 2; ++h) {
        const int tt = t + h * 256;          // 512 (nb,ks,l) triples
        const int nb = tt >> 7, ks = (tt >> 6) & 1, l = tt & 63;
        const int o  = nb * 16 + (l & 15);
        const int k0 = ks * 32 + (l >> 4) * 8;
        #pragma unroll
        for (int j = 0; j < 4; ++j) {
            const float a = z[(k0 + 2*j    ) * 64 + o];
            const float b = z[(k0 + 2*j + 1) * 64 + o];
            const unsigned short ha = bf16_rne(a), hb = bf16_rne(b);
            const float ra = a - bf16_f(ha);
            const float rb = b - bf16_f(hb);
            const int idx = ((nb * 2 + ks) * 64 + l) * 4 + j;
            wsu[idx]        = (unsigned)ha | ((unsigned)hb << 16);
            wsu[2048 + idx] = (unsigned)bf16_rne(ra) | ((unsigned)bf16_rne(rb) << 16);
        }
    }
    if (t < 64) {
        const int o = t;
        float n2 = 0.f;
        for (int k = 0; k < 64; ++k) { const float v = z[k*64 + o]; n2 = fmaf(v, v, n2); }
        const float zn = fmaxf(sqrtf(n2), 1e-15f);
        const float e  = expf(2.f * bias[o]);
        const float ei = 1.f / e;
        float4 c;
        c.x = 0.5f * (e + ei) / zn;    // K1
        c.y = 0.5f * (e - ei);         // K2
        c.z = 2.f * zn;                // K4
        c.w = 0.f;
        reinterpret_cast<float4*>(ws + 4096)[o] = c;
    }
}

__device__ __forceinline__ float hl_chain(float xz, float lam,
                                          float K1, float K2, float K4) {
    const float u  = fmaf(lam, fmaf(xz, K1, -K2), K2);
    const float au = fabsf(u);
    const float sq = __builtin_amdgcn_sqrtf(fmaf(au, au, 1.f));
    const float lg = __builtin_amdgcn_logf(au + sq);      // log2
    const float e  = __builtin_amdgcn_exp2f(K4 * lg);     // 2^x
    const float ei = __builtin_amdgcn_rcpf(e);
    return copysignf(fmaf(0.5f, e, -0.5f * ei), u);       // sinh
}

// split one f32 pair into packed-bf16 hi + residual-lo dwords (6 instr)
__device__ __forceinline__ void split2(float a, float b,
                                       unsigned int& ph, unsigned int& pl) {
    asm("v_cvt_pk_bf16_f32 %0, %1, %2" : "=v"(ph) : "v"(a), "v"(b));
    const float fa = __uint_as_float(ph << 16);            // bf16(a) as f32
    const float fb = __uint_as_float(ph & 0xffff0000u);    // bf16(b) as f32
    asm("v_cvt_pk_bf16_f32 %0, %1, %2" : "=v"(pl) : "v"(a - fa), "v"(b - fb));
}

__device__ __forceinline__ void build_frag(const float4& f0, const float4& f1,
                                           uint4& hi, uint4& lo) {
    split2(f0.x, f0.y, hi.x, lo.x);
    split2(f0.z, f0.w, hi.y, lo.y);
    split2(f1.x, f1.y, hi.z, lo.z);
    split2(f1.z, f1.w, hi.w, lo.w);
}

#define MFMA(A, B, C) __builtin_amdgcn_mfma_f32_16x16x32_bf16( \
    __builtin_bit_cast(bf16x8, A), __builtin_bit_cast(bf16x8, B), C, 0, 0, 0)

__global__ __launch_bounds__(256, 7)
void hl_mfma(const float* __restrict__ x, const float* __restrict__ ws_f,
             float* __restrict__ out) {
    __shared__ unsigned int ldsb[4096];      // B hi [0,2048) + lo [2048,4096)
    __shared__ float4       ldsk[64];        // per-o constants

    const unsigned int* __restrict__ wsu = reinterpret_cast<const unsigned int*>(ws_f);
    const int tid  = threadIdx.x;
    const int wave = tid >> 6;
    const int l    = tid & 63;
    const int half = l >> 4;                 // k-chunk 0..3
    const int o0   = l & 15;
    const long rowbase = (long)blockIdx.x * 64 + wave * 16;

    // ---- issue own x loads FIRST (HBM latency overlaps staging+barrier) ----
    const float* __restrict__ xp = x + (rowbase + o0) * 64 + half * 8;
    const float4 xa0 = *reinterpret_cast<const float4*>(xp);
    const float4 xa1 = *reinterpret_cast<const float4*>(xp + 4);
    const float4 xb0 = *reinterpret_cast<const float4*>(xp + 32);
    const float4 xb1 = *reinterpret_cast<const float4*>(xp + 36);

    // ---- cooperative stage: B hi/lo + kc -> LDS (once per block) ----
    {
        const uint4* __restrict__ src = reinterpret_cast<const uint4*>(wsu);
        uint4* __restrict__ dst = reinterpret_cast<uint4*>(ldsb);
        #pragma unroll
        for (int t = 0; t < 4; ++t) dst[t * 256 + tid] = src[t * 256 + tid];
        if (tid < 64) ldsk[tid] = reinterpret_cast<const float4*>(ws_f + 4096)[tid];
    }

    // ---- row norm (exact f32): partial over this lane's 16 k, reduce x4 ----
    float n2 = 0.f;
    n2 = fmaf(xa0.x,xa0.x,n2); n2 = fmaf(xa0.y,xa0.y,n2);
    n2 = fmaf(xa0.z,xa0.z,n2); n2 = fmaf(xa0.w,xa0.w,n2);
    n2 = fmaf(xa1.x,xa1.x,n2); n2 = fmaf(xa1.y,xa1.y,n2);
    n2 = fmaf(xa1.z,xa1.z,n2); n2 = fmaf(xa1.w,xa1.w,n2);
    n2 = fmaf(xb0.x,xb0.x,n2); n2 = fmaf(xb0.y,xb0.y,n2);
    n2 = fmaf(xb0.z,xb0.z,n2); n2 = fmaf(xb0.w,xb0.w,n2);
    n2 = fmaf(xb1.x,xb1.x,n2); n2 = fmaf(xb1.y,xb1.y,n2);
    n2 = fmaf(xb1.z,xb1.z,n2); n2 = fmaf(xb1.w,xb1.w,n2);
    n2 += __shfl_xor(n2, 16);
    n2 += __shfl_xor(n2, 32);
    const float lamv = 2.f * __builtin_amdgcn_rcpf(1.f - n2);   // row (l&15)

    // ---- A fragments (hi/lo split via cvt_pk_bf16) ----
    uint4 Ah0, Al0, Ah1, Al1;
    build_frag(xa0, xa1, Ah0, Al0);
    build_frag(xb0, xb1, Ah1, Al1);

    // ---- lam for this lane's 4 C-rows (row = half*4 + reg) ----
    float lam_r[4];
    #pragma unroll
    for (int reg = 0; reg < 4; ++reg)
        lam_r[reg] = __shfl(lamv, half * 4 + reg);

    __syncthreads();                         // staging complete

    // ---- per-nb: B frags (LDS) -> 6 MFMA -> chain 4 -> pack w to fp16 ----
    const uint4* __restrict__ lb = reinterpret_cast<const uint4*>(ldsb);
    unsigned int wpk[8];                     // 16 w values, fp16-packed
    float p[4] = {0.f, 0.f, 0.f, 0.f};       // per-C-row sum(w^2) partials
    #pragma unroll 1
    for (int nb = 0; nb < 4; ++nb) {
        const uint4 bh0 = lb[      (nb*2+0)*64 + l];
        const uint4 bl0 = lb[512 + (nb*2+0)*64 + l];
        const uint4 bh1 = lb[      (nb*2+1)*64 + l];
        const uint4 bl1 = lb[512 + (nb*2+1)*64 + l];
        const float4 kc = ldsk[nb*16 + o0];

        f32x4 a = {0.f, 0.f, 0.f, 0.f};
        a = MFMA(Al0, bh0, a);   // low-order terms first
        a = MFMA(Ah0, bl0, a);
        a = MFMA(Ah0, bh0, a);
        a = MFMA(Al1, bh1, a);
        a = MFMA(Ah1, bl1, a);
        a = MFMA(Ah1, bh1, a);

        float w0 = hl_chain(a[0], lam_r[0], kc.x, kc.y, kc.z);
        float w1 = hl_chain(a[1], lam_r[1], kc.x, kc.y, kc.z);
        float w2 = hl_chain(a[2], lam_r[2], kc.x, kc.y, kc.z);
        float w3 = hl_chain(a[3], lam_r[3], kc.x, kc.y, kc.z);
        p[0] = fmaf(w0, w0, p[0]);
        p[1] = fmaf(w1, w1, p[1]);
        p[2] = fmaf(w2, w2, p[2]);
        p[3] = fmaf(w3, w3, p[3]);
        h2 q0 = __builtin_amdgcn_cvt_pkrtz(w0, w1);
        h2 q1 = __builtin_amdgcn_cvt_pkrtz(w2, w3);
        wpk[nb*2]   = __builtin_bit_cast(unsigned int, q0);
        wpk[nb*2+1] = __builtin_bit_cast(unsigned int, q1);
    }

    // ---- reduce sum(w^2) over the 16-lane group (all 64 o of each row) ----
    #pragma unroll
    for (int reg = 0; reg < 4; ++reg) {
        p[reg] += __shfl_xor(p[reg], 1);
        p[reg] += __shfl_xor(p[reg], 2);
        p[reg] += __shfl_xor(p[reg], 4);
        p[reg] += __shfl_xor(p[reg], 8);
    }

    // ---- scale + NON-TEMPORAL stores: 64B-coalesced per 16-lane group ----
    #pragma unroll
    for (int reg = 0; reg < 4; ++reg) {
        const float scale =
            __builtin_amdgcn_rcpf(1.f + __builtin_amdgcn_sqrtf(1.f + p[reg]));
        float* __restrict__ orow = out + (rowbase + half * 4 + reg) * 64 + o0;
        #pragma unroll
        for (int nb = 0; nb < 4; ++nb) {
            const h2 q = __builtin_bit_cast(h2, wpk[nb*2 + (reg >> 1)]);
            __builtin_nontemporal_store((float)q[reg & 1] * scale, orow + nb * 16);
        }
    }
}

// slow correctness fallback (only if ws too small; never expected to run)
__global__ void hl_naive(const float* __restrict__ x, const float* __restrict__ z,
                         const float* __restrict__ bias, float* __restrict__ out,
                         long rows) {
    const long r = (long)blockIdx.x * blockDim.x + threadIdx.x;
    if (r >= rows) return;
    float xs[64];
    float n2 = 0.f;
    for (int k = 0; k < 64; ++k) { xs[k] = x[r*64 + k]; n2 = fmaf(xs[k], xs[k], n2); }
    const float lam = 2.f / (1.f - n2);
    float wv[64], sw2 = 0.f;
    for (int o = 0; o < 64; ++o) {
        float a = 0.f, q = 0.f;
        for (int k = 0; k < 64; ++k) {
            const float zv = z[k*64 + o];
            a = fmaf(zv, xs[k], a);
            q = fmaf(zv, zv, q);
        }
        const float zn = fmaxf(sqrtf(q), 1e-15f);
        const float e  = expf(2.f * bias[o]);
        const float ei = 1.f / e;
        wv[o] = hl_chain(a, lam, 0.5f*(e+ei)/zn, 0.5f*(e-ei), 2.f*zn);
        sw2 = fmaf(wv[o], wv[o], sw2);
    }
    const float s = 1.f / (1.f + sqrtf(1.f + sw2));
    for (int o = 0; o < 64; ++o) out[r*64 + o] = wv[o] * s;
}

extern "C" void kernel_launch(void* const* d_in, const int* in_sizes, int n_in,
                              void* d_out, int out_size, void* d_ws, size_t ws_size,
                              hipStream_t stream) {
    const float* x    = (const float*)d_in[0];
    const float* z    = (const float*)d_in[1];
    const float* bias = (const float*)d_in[2];
    float* out = (float*)d_out;
    float* ws  = (float*)d_ws;

    const long rows = (long)in_sizes[0] / 64;       // 1048576

    if (ws_size >= (size_t)(4096 + 256) * sizeof(unsigned int)) {
        hl_prep<<<1, 256, 0, stream>>>(z, bias, ws);
        hl_mfma<<<(int)(rows / 64), 256, 0, stream>>>(x, ws, out);
    } else {
        hl_naive<<<(int)((rows + 255) / 256), 256, 0, stream>>>(x, z, bias, out, rows);
    }
}

// Round 18
// 99.351 us; speedup vs baseline: 1.2479x; 1.0058x over previous
//
#include <hip/hip_runtime.h>
#include <math.h>

// Poincare fully-connected (hypll / Shimizu et al.), c = 1.
// B=1048576, IN=64, OUT=64, all fp32.
//
// R18 = byte-exact revert to R16 (99.9 us, passing):
//   split-bf16 MFMA dot (x=xh+xl, z=zh+zl; xz = Al*Bh+Ah*Bl+Ah*Bh via
//   3x mfma_f32_16x16x32_bf16); B/kc staged in LDS once per block;
//   cvt_pk_bf16 frag split; fp16-packed w; NON-TEMPORAL 64B-coalesced
//   stores; __launch_bounds__(256,7).
// R17's TPB=4 variant was algebraically identical but miscompiled under
// the 73-VGPR cap (absmax 4.5e-2) - multi-tile abandoned (R14/R17).
// Block = 256 = 4 waves; wave = 16 rows; grid = rows/64.

typedef short bf16x8 __attribute__((ext_vector_type(8)));
typedef float f32x4  __attribute__((ext_vector_type(4)));
typedef __fp16 h2    __attribute__((ext_vector_type(2)));

__device__ __forceinline__ unsigned short bf16_rne(float f) {
    unsigned int u = __float_as_uint(f);
    return (unsigned short)((u + 0x7fffu + ((u >> 16) & 1u)) >> 16);
}
__device__ __forceinline__ float bf16_f(unsigned short h) {
    return __uint_as_float((unsigned int)h << 16);
}

// ws u32 layout:
//   [0,2048)    : B_hi dwords, idx ((nb*2+ks)*64 + lane)*4 + j
//   [2048,4096) : B_lo dwords, same idx
//   [4096,4352) : kc float4[o] = {K1, K2, K4, 0}
__global__ void hl_prep(const float* __restrict__ z, const float* __restrict__ bias,
                        float* __restrict__ ws) {
    unsigned int* wsu = reinterpret_cast<unsigned int*>(ws);
    const int t = threadIdx.x;
    #pragma unroll
    for (int h = 0; h < 2; ++h) {
        const int tt = t + h * 256;          // 512 (nb,ks,l) triples
        const int nb = tt >> 7, ks = (tt >> 6) & 1, l = tt & 63;
        const int o  = nb * 16 + (l & 15);
        const int k0 = ks * 32 + (l >> 4) * 8;
        #pragma unroll
        for (int j = 0; j < 4; ++j) {
            const float a = z[(k0 + 2*j    ) * 64 + o];
            const float b = z[(k0 + 2*j + 1) * 64 + o];
            const unsigned short ha = bf16_rne(a), hb = bf16_rne(b);
            const float ra = a - bf16_f(ha);
            const float rb = b - bf16_f(hb);
            const int idx = ((nb * 2 + ks) * 64 + l) * 4 + j;
            wsu[idx]        = (unsigned)ha | ((unsigned)hb << 16);
            wsu[2048 + idx] = (unsigned)bf16_rne(ra) | ((unsigned)bf16_rne(rb) << 16);
        }
    }
    if (t < 64) {
        const int o = t;
        float n2 = 0.f;
        for (int k = 0; k < 64; ++k) { const float v = z[k*64 + o]; n2 = fmaf(v, v, n2); }
        const float zn = fmaxf(sqrtf(n2), 1e-15f);
        const float e  = expf(2.f * bias[o]);
        const float ei = 1.f / e;
        float4 c;
        c.x = 0.5f * (e + ei) / zn;    // K1
        c.y = 0.5f * (e - ei);         // K2
        c.z = 2.f * zn;                // K4
        c.w = 0.f;
        reinterpret_cast<float4*>(ws + 4096)[o] = c;
    }
}

__device__ __forceinline__ float hl_chain(float xz, float lam,
                                          float K1, float K2, float K4) {
    const float u  = fmaf(lam, fmaf(xz, K1, -K2), K2);
    const float au = fabsf(u);
    const float sq = __builtin_amdgcn_sqrtf(fmaf(au, au, 1.f));
    const float lg = __builtin_amdgcn_logf(au + sq);      // log2
    const float e  = __builtin_amdgcn_exp2f(K4 * lg);     // 2^x
    const float ei = __builtin_amdgcn_rcpf(e);
    return copysignf(fmaf(0.5f, e, -0.5f * ei), u);       // sinh
}

// split one f32 pair into packed-bf16 hi + residual-lo dwords (6 instr)
__device__ __forceinline__ void split2(float a, float b,
                                       unsigned int& ph, unsigned int& pl) {
    asm("v_cvt_pk_bf16_f32 %0, %1, %2" : "=v"(ph) : "v"(a), "v"(b));
    const float fa = __uint_as_float(ph << 16);            // bf16(a) as f32
    const float fb = __uint_as_float(ph & 0xffff0000u);    // bf16(b) as f32
    asm("v_cvt_pk_bf16_f32 %0, %1, %2" : "=v"(pl) : "v"(a - fa), "v"(b - fb));
}

__device__ __forceinline__ void build_frag(const float4& f0, const float4& f1,
                                           uint4& hi, uint4& lo) {
    split2(f0.x, f0.y, hi.x, lo.x);
    split2(f0.z, f0.w, hi.y, lo.y);
    split2(f1.x, f1.y, hi.z, lo.z);
    split2(f1.z, f1.w, hi.w, lo.w);
}

#define MFMA(A, B, C) __builtin_amdgcn_mfma_f32_16x16x32_bf16( \
    __builtin_bit_cast(bf16x8, A), __builtin_bit_cast(bf16x8, B), C, 0, 0, 0)

__global__ __launch_bounds__(256, 7)
void hl_mfma(const float* __restrict__ x, const float* __restrict__ ws_f,
             float* __restrict__ out) {
    __shared__ unsigned int ldsb[4096];      // B hi [0,2048) + lo [2048,4096)
    __shared__ float4       ldsk[64];        // per-o constants

    const unsigned int* __restrict__ wsu = reinterpret_cast<const unsigned int*>(ws_f);
    const int tid  = threadIdx.x;
    const int wave = tid >> 6;
    const int l    = tid & 63;
    const int half = l >> 4;                 // k-chunk 0..3
    const int o0   = l & 15;
    const long rowbase = (long)blockIdx.x * 64 + wave * 16;

    // ---- issue own x loads FIRST (HBM latency overlaps staging+barrier) ----
    const float* __restrict__ xp = x + (rowbase + o0) * 64 + half * 8;
    const float4 xa0 = *reinterpret_cast<const float4*>(xp);
    const float4 xa1 = *reinterpret_cast<const float4*>(xp + 4);
    const float4 xb0 = *reinterpret_cast<const float4*>(xp + 32);
    const float4 xb1 = *reinterpret_cast<const float4*>(xp + 36);

    // ---- cooperative stage: B hi/lo + kc -> LDS (once per block) ----
    {
        const uint4* __restrict__ src = reinterpret_cast<const uint4*>(wsu);
        uint4* __restrict__ dst = reinterpret_cast<uint4*>(ldsb);
        #pragma unroll
        for (int t = 0; t < 4; ++t) dst[t * 256 + tid] = src[t * 256 + tid];
        if (tid < 64) ldsk[tid] = reinterpret_cast<const float4*>(ws_f + 4096)[tid];
    }

    // ---- row norm (exact f32): partial over this lane's 16 k, reduce x4 ----
    float n2 = 0.f;
    n2 = fmaf(xa0.x,xa0.x,n2); n2 = fmaf(xa0.y,xa0.y,n2);
    n2 = fmaf(xa0.z,xa0.z,n2); n2 = fmaf(xa0.w,xa0.w,n2);
    n2 = fmaf(xa1.x,xa1.x,n2); n2 = fmaf(xa1.y,xa1.y,n2);
    n2 = fmaf(xa1.z,xa1.z,n2); n2 = fmaf(xa1.w,xa1.w,n2);
    n2 = fmaf(xb0.x,xb0.x,n2); n2 = fmaf(xb0.y,xb0.y,n2);
    n2 = fmaf(xb0.z,xb0.z,n2); n2 = fmaf(xb0.w,xb0.w,n2);
    n2 = fmaf(xb1.x,xb1.x,n2); n2 = fmaf(xb1.y,xb1.y,n2);
    n2 = fmaf(xb1.z,xb1.z,n2); n2 = fmaf(xb1.w,xb1.w,n2);
    n2 += __shfl_xor(n2, 16);
    n2 += __shfl_xor(n2, 32);
    const float lamv = 2.f * __builtin_amdgcn_rcpf(1.f - n2);   // row (l&15)

    // ---- A fragments (hi/lo split via cvt_pk_bf16) ----
    uint4 Ah0, Al0, Ah1, Al1;
    build_frag(xa0, xa1, Ah0, Al0);
    build_frag(xb0, xb1, Ah1, Al1);

    // ---- lam for this lane's 4 C-rows (row = half*4 + reg) ----
    float lam_r[4];
    #pragma unroll
    for (int reg = 0; reg < 4; ++reg)
        lam_r[reg] = __shfl(lamv, half * 4 + reg);

    __syncthreads();                         // staging complete

    // ---- per-nb: B frags (LDS) -> 6 MFMA -> chain 4 -> pack w to fp16 ----
    const uint4* __restrict__ lb = reinterpret_cast<const uint4*>(ldsb);
    unsigned int wpk[8];                     // 16 w values, fp16-packed
    float p[4] = {0.f, 0.f, 0.f, 0.f};       // per-C-row sum(w^2) partials
    #pragma unroll 1
    for (int nb = 0; nb < 4; ++nb) {
        const uint4 bh0 = lb[      (nb*2+0)*64 + l];
        const uint4 bl0 = lb[512 + (nb*2+0)*64 + l];
        const uint4 bh1 = lb[      (nb*2+1)*64 + l];
        const uint4 bl1 = lb[512 + (nb*2+1)*64 + l];
        const float4 kc = ldsk[nb*16 + o0];

        f32x4 a = {0.f, 0.f, 0.f, 0.f};
        a = MFMA(Al0, bh0, a);   // low-order terms first
        a = MFMA(Ah0, bl0, a);
        a = MFMA(Ah0, bh0, a);
        a = MFMA(Al1, bh1, a);
        a = MFMA(Ah1, bl1, a);
        a = MFMA(Ah1, bh1, a);

        float w0 = hl_chain(a[0], lam_r[0], kc.x, kc.y, kc.z);
        float w1 = hl_chain(a[1], lam_r[1], kc.x, kc.y, kc.z);
        float w2 = hl_chain(a[2], lam_r[2], kc.x, kc.y, kc.z);
        float w3 = hl_chain(a[3], lam_r[3], kc.x, kc.y, kc.z);
        p[0] = fmaf(w0, w0, p[0]);
        p[1] = fmaf(w1, w1, p[1]);
        p[2] = fmaf(w2, w2, p[2]);
        p[3] = fmaf(w3, w3, p[3]);
        h2 q0 = __builtin_amdgcn_cvt_pkrtz(w0, w1);
        h2 q1 = __builtin_amdgcn_cvt_pkrtz(w2, w3);
        wpk[nb*2]   = __builtin_bit_cast(unsigned int, q0);
        wpk[nb*2+1] = __builtin_bit_cast(unsigned int, q1);
    }

    // ---- reduce sum(w^2) over the 16-lane group (all 64 o of each row) ----
    #pragma unroll
    for (int reg = 0; reg < 4; ++reg) {
        p[reg] += __shfl_xor(p[reg], 1);
        p[reg] += __shfl_xor(p[reg], 2);
        p[reg] += __shfl_xor(p[reg], 4);
        p[reg] += __shfl_xor(p[reg], 8);
    }

    // ---- scale + NON-TEMPORAL stores: 64B-coalesced per 16-lane group ----
    #pragma unroll
    for (int reg = 0; reg < 4; ++reg) {
        const float scale =
            __builtin_amdgcn_rcpf(1.f + __builtin_amdgcn_sqrtf(1.f + p[reg]));
        float* __restrict__ orow = out + (rowbase + half * 4 + reg) * 64 + o0;
        #pragma unroll
        for (int nb = 0; nb < 4; ++nb) {
            const h2 q = __builtin_bit_cast(h2, wpk[nb*2 + (reg >> 1)]);
            __builtin_nontemporal_store((float)q[reg & 1] * scale, orow + nb * 16);
        }
    }
}

// slow correctness fallback (only if ws too small; never expected to run)
__global__ void hl_naive(const float* __restrict__ x, const float* __restrict__ z,
                         const float* __restrict__ bias, float* __restrict__ out,
                         long rows) {
    const long r = (long)blockIdx.x * blockDim.x + threadIdx.x;
    if (r >= rows) return;
    float xs[64];
    float n2 = 0.f;
    for (int k = 0; k < 64; ++k) { xs[k] = x[r*64 + k]; n2 = fmaf(xs[k], xs[k], n2); }
    const float lam = 2.f / (1.f - n2);
    float wv[64], sw2 = 0.f;
    for (int o = 0; o < 64; ++o) {
        float a = 0.f, q = 0.f;
        for (int k = 0; k < 64; ++k) {
            const float zv = z[k*64 + o];
            a = fmaf(zv, xs[k], a);
            q = fmaf(zv, zv, q);
        }
        const float zn = fmaxf(sqrtf(q), 1e-15f);
        const float e  = expf(2.f * bias[o]);
        const float ei = 1.f / e;
        wv[o] = hl_chain(a, lam, 0.5f*(e+ei)/zn, 0.5f*(e-ei), 2.f*zn);
        sw2 = fmaf(wv[o], wv[o], sw2);
    }
    const float s = 1.f / (1.f + sqrtf(1.f + sw2));
    for (int o = 0; o < 64; ++o) out[r*64 + o] = wv[o] * s;
}

extern "C" void kernel_launch(void* const* d_in, const int* in_sizes, int n_in,
                              void* d_out, int out_size, void* d_ws, size_t ws_size,
                              hipStream_t stream) {
    const float* x    = (const float*)d_in[0];
    const float* z    = (const float*)d_in[1];
    const float* bias = (const float*)d_in[2];
    float* out = (float*)d_out;
    float* ws  = (float*)d_ws;

    const long rows = (long)in_sizes[0] / 64;       // 1048576

    if (ws_size >= (size_t)(4096 + 256) * sizeof(unsigned int)) {
        hl_prep<<<1, 256, 0, stream>>>(z, bias, ws);
        hl_mfma<<<(int)(rows / 64), 256, 0, stream>>>(x, ws, out);
    } else {
        hl_naive<<<(int)((rows + 255) / 256), 256, 0, stream>>>(x, z, bias, out, rows);
    }
}